// Round 18
// baseline (238.930 us; speedup 1.0000x reference)
//
#include <hip/hip_runtime.h>
#include <hip/hip_bf16.h>

#define NIN 1024
#define NL 128
#define MS 16384    // 128x128 matrix slot (elements)
#define CMS 32768   // 256x128 C slot (elements)

typedef __attribute__((ext_vector_type(8))) short bf16x8_t;
typedef __attribute__((ext_vector_type(4))) float f32x4_t;

__device__ inline unsigned short f2bf(float f) {
    __hip_bfloat16 h = __float2bfloat16(f);
    return *reinterpret_cast<unsigned short*>(&h);
}
__device__ inline ushort4 pack4(f32x4_t v) {
    ushort4 o;
    o.x = f2bf(v[0]); o.y = f2bf(v[1]); o.z = f2bf(v[2]); o.w = f2bf(v[3]);
    return o;
}

// ---- chain task: D(32x128) = A(32 rows) @ B0 [@ B1 [@ B2]] ----------------
// Intermediate kept in LDS transposed [col][row]; ~1us per stage per block.
// lds usage: Bl 32KB + 2 x [128][33] f32 (33KB) = 65KB.
__device__ __forceinline__ void pmmChain(const float* __restrict__ Ag,
                                         const float* B0, const float* B1,
                                         const float* B2, int nst,
                                         float* __restrict__ D,
                                         unsigned short* __restrict__ Db,
                                         char* lds) {
    float* Bl = (float*)lds;               // [128][64] 32 KB
    float* cur = (float*)(lds + 32768);    // [128][33]
    float* nxt = cur + 128 * 33;           // [128][33]
    int t = threadIdx.x;
    // stage A transposed: cur[kk][m] = Ag[m][kk]
    for (int idx = t; idx < 4096; idx += 256) {
        int m = idx >> 7, kk = idx & 127;
        cur[kk * 33 + m] = Ag[(size_t)m * NL + kk];
    }
    const float* Bs[3] = {B0, B1, B2};
    for (int s = 0; s < nst; ++s) {
        const float* B = Bs[s];
#pragma unroll
        for (int jh = 0; jh < 2; ++jh) {
            __syncthreads();  // prior reads of Bl / writes of cur done
            for (int idx = t; idx < 2048; idx += 256) {
                int row = idx >> 4, c = idx & 15;
                *(float4*)&Bl[row * 64 + c * 4] =
                    *(const float4*)&B[row * NL + jh * 64 + c * 4];
            }
            __syncthreads();
            int j = t & 63, rg = t >> 6;  // rg is wave-uniform
            float acc[8];
#pragma unroll
            for (int q = 0; q < 8; ++q) acc[q] = 0.f;
#pragma unroll 4
            for (int kk = 0; kk < 128; ++kk) {
                float bv = Bl[kk * 64 + j];
                const float* ap = &cur[kk * 33 + rg * 8];
#pragma unroll
                for (int q = 0; q < 8; ++q) acc[q] += ap[q] * bv;
            }
#pragma unroll
            for (int q = 0; q < 8; ++q)
                nxt[(jh * 64 + j) * 33 + rg * 8 + q] = acc[q];
        }
        __syncthreads();
        float* tmp = cur; cur = nxt; nxt = tmp;
    }
    // cur[col][m] holds result; write out coalesced by col
    for (int idx = t; idx < 4096; idx += 256) {
        int m = idx >> 7, col = idx & 127;
        float v = cur[col * 33 + m];
        D[(size_t)m * NL + col] = v;
        if (Db) Db[(size_t)m * NL + col] = f2bf(v);
    }
}

// H tile (bf16 MFMA, swapped operands): H[(n*16+a)][m] = sum_l F[n,l]*T^{a+1}[m,l]
__device__ __forceinline__ void hmfma(const unsigned short* __restrict__ Fb,
                                      const unsigned short* __restrict__ Wa,
                                      unsigned short* __restrict__ H,
                                      int a, int nt, char* lds) {
    char* lB = lds;  // swizzled T tile, 32 KB
    int t = threadIdx.x;
    for (int i = t; i < 2048; i += 256) {
        int row = i >> 4, c = i & 15;
        int sw = (c * 16) ^ ((row & 7) << 4);
        *(bf16x8_t*)(lB + row * 256 + sw) = *(const bf16x8_t*)(Wa + (size_t)row * NL + c * 8);
    }
    __syncthreads();
    int w = t >> 6, lane = t & 63;
    int wn = (w >> 1) * 64, wm = (w & 1) * 64;
    int r = lane & 15, g = lane >> 4;
    const unsigned short* Ag = Fb + (size_t)(nt * 128) * NL;
    bf16x8_t av[4][4];  // [kk][aa]
#pragma unroll
    for (int kk = 0; kk < 4; ++kk) {
        int c16 = kk * 4 + g;
#pragma unroll
        for (int aa = 0; aa < 4; ++aa)
            av[kk][aa] = *(const bf16x8_t*)(Ag + (size_t)(wn + aa * 16 + r) * NL + c16 * 8);
    }
    f32x4_t acc[4][4];
#pragma unroll
    for (int aa = 0; aa < 4; ++aa)
#pragma unroll
        for (int bb = 0; bb < 4; ++bb) acc[aa][bb] = (f32x4_t){0.f, 0.f, 0.f, 0.f};
#pragma unroll
    for (int kk = 0; kk < 4; ++kk) {
        int c16 = kk * 4 + g;
        bf16x8_t bv[4];
#pragma unroll
        for (int bb = 0; bb < 4; ++bb) {
            int rowB = wm + bb * 16 + r;
            bv[bb] = *(const bf16x8_t*)(lB + rowB * 256 + ((c16 * 16) ^ ((rowB & 7) << 4)));
        }
#pragma unroll
        for (int aa = 0; aa < 4; ++aa)
#pragma unroll
            for (int bb = 0; bb < 4; ++bb)
                acc[aa][bb] = __builtin_amdgcn_mfma_f32_16x16x32_bf16(bv[bb], av[kk][aa], acc[aa][bb], 0, 0, 0);
    }
#pragma unroll
    for (int aa = 0; aa < 4; ++aa) {
        int n = nt * 128 + wn + aa * 16 + r;
#pragma unroll
        for (int bb = 0; bb < 4; ++bb) {
            int m0 = wm + bb * 16 + g * 4;
            *(ushort4*)&H[((size_t)n * 16 + a) * NL + m0] = pack4(acc[aa][bb]);
        }
    }
}

// ---------------- preamble: 5 phases (max 3-stage chains) -------------------
// W slots: s holds T^{s+1} for s=0..15; 16 = T^32; 17 = T^64.
// ph0 (100): lat0(32) | copies(64) | T2 = tr@tr (4)
// ph1 (16):  T3 = T1@T4?  no: T3 = T1@T2, T4 = T2@T2, T5 = T1@T2@T2, T6 = T2@T2@T2
// ph2 (40):  T7..T16 from {T1..T4}: A-slot (mi+2)&3, B = T4 x nst,
//            nst = 1 + (mi>=2) + (mi>=6)   [power: (Aslot+1) + 4*nst = 7+mi]
// ph3 (160): H(128) | T32 = T16@T16 (4) | T64 = T16@T16^3 (4)
//            | C1 = C0@T16 (8) | C2 = C0@T16^2 (8) | C3 = C0@T16^3 (8)
// ph4 (96):  C4..7 = C0..3@T64 | C8..11 = @T64^2 | C12..15 = @T64^3
__global__ __launch_bounds__(256) void k_phase(int ph,
                                               const float* __restrict__ x,
                                               const float* __restrict__ tf,
                                               const float* __restrict__ tr,
                                               float* __restrict__ W,
                                               unsigned short* __restrict__ Wb,
                                               unsigned short* __restrict__ Fb,
                                               float* __restrict__ Cf,
                                               unsigned short* __restrict__ Cc,
                                               unsigned short* __restrict__ H) {
    __shared__ __align__(16) char lds[66560];  // 65 KB (chain worst case)
    int blk = blockIdx.x, t = threadIdx.x;
    if (ph == 0) {
        if (blk < 32) {
            // lat0: 8 b-rows per block; thread owns 4 cols (f32x4 tf loads)
            float* xr = (float*)lds;  // [8][1024] 32 KB
            int b0 = blk * 8;
            for (int idx = t; idx < 2048; idx += 256) {
                int rr = idx >> 8, c = idx & 255;
                ((float4*)xr)[rr * 256 + c] =
                    ((const float4*)(x + (size_t)(b0 + rr) * NIN))[c];
            }
            __syncthreads();
            int cg = t & 31, rs = t >> 5;
            const float* xp = xr + rs * NIN;
            f32x4_t acc = (f32x4_t){0.f, 0.f, 0.f, 0.f};
#pragma unroll 8
            for (int i = 0; i < NIN; ++i) {
                f32x4_t tv = *(const f32x4_t*)&tf[i * NL + cg * 4];
                acc += xp[i] * tv;
            }
            int row = b0 + rs;
            *(f32x4_t*)&Cf[(size_t)row * NL + cg * 4] = acc;
            *(ushort4*)&Cc[(size_t)row * NL + cg * 4] = pack4(acc);
        } else if (blk < 96) {
            int id = (blk - 32) * 256 + t;  // 0..16383
            float v = tr[id];
            W[id] = v;
            Wb[id] = f2bf(v);
            for (int i = id; i < NIN * NL; i += 16384) Fb[i] = f2bf(tf[i]);
        } else {
            // T2 = tr @ tr -> slot 1 (4 row-tiles)
            int r0 = (blk - 96) * 32;
            pmmChain(tr + (size_t)r0 * NL, tr, nullptr, nullptr, 1,
                     W + MS + (size_t)r0 * NL, Wb + MS + (size_t)r0 * NL, lds);
        }
    } else if (ph == 1) {
        int mi = blk >> 2, r0 = (blk & 3) * 32;
        // T3 = T1@T2; T4 = T2@T2; T5 = T1@T2@T2; T6 = T2@T2@T2
        const float* A = W + (size_t)(mi & 1) * MS;  // mi even -> T1, odd -> T2
        int nst = 1 + (mi >> 1);
        int dst = 2 + mi;
        pmmChain(A + (size_t)r0 * NL, W + MS, W + MS, nullptr, nst,
                 W + (size_t)dst * MS + (size_t)r0 * NL,
                 Wb + (size_t)dst * MS + (size_t)r0 * NL, lds);
    } else if (ph == 2) {
        int mi = blk >> 2, r0 = (blk & 3) * 32;  // mi 0..9 -> T^{7+mi}
        const float* A = W + (size_t)((mi + 2) & 3) * MS;
        int nst = 1 + (mi >= 2) + (mi >= 6);
        int dst = 6 + mi;
        const float* T4p = W + 3 * (size_t)MS;
        pmmChain(A + (size_t)r0 * NL, T4p, T4p, T4p, nst,
                 W + (size_t)dst * MS + (size_t)r0 * NL,
                 Wb + (size_t)dst * MS + (size_t)r0 * NL, lds);
    } else if (ph == 3) {
        const float* T16p = W + 15 * (size_t)MS;
        if (blk < 128) {
            hmfma(Fb, Wb + (size_t)(blk >> 3) * MS, H, blk >> 3, blk & 7, lds);
        } else if (blk < 132) {
            int r0 = (blk - 128) * 32;  // T32 -> slot 16 (f32 only)
            pmmChain(T16p + (size_t)r0 * NL, T16p, nullptr, nullptr, 1,
                     W + 16 * (size_t)MS + (size_t)r0 * NL, nullptr, lds);
        } else if (blk < 136) {
            int r0 = (blk - 132) * 32;  // T64 = T16^4 -> slot 17
            pmmChain(T16p + (size_t)r0 * NL, T16p, T16p, T16p, 3,
                     W + 17 * (size_t)MS + (size_t)r0 * NL, nullptr, lds);
        } else {
            // C1,C2,C3 = C0 @ T16^{1,2,3} (8 row-tiles each, 256 rows)
            int rel = blk - 136, ci = rel >> 3, r0 = (rel & 7) * 32;
            int nst = ci + 1;
            pmmChain(Cf + (size_t)r0 * NL, T16p, T16p, T16p, nst,
                     Cf + (size_t)(1 + ci) * CMS + (size_t)r0 * NL,
                     Cc + (size_t)(1 + ci) * CMS + (size_t)r0 * NL, lds);
        }
    } else {
        // C{4+4*k+q} = C_q @ T64^{k+1}, k=0..2, q=0..3
        int mi = blk >> 3, r0 = (blk & 7) * 32;
        int q = mi & 3, k = mi >> 2;
        const float* T64p = W + 17 * (size_t)MS;
        int dst = 4 + k * 4 + q;
        pmmChain(Cf + (size_t)q * CMS + (size_t)r0 * NL, T64p, T64p, T64p, k + 1,
                 Cf + (size_t)dst * CMS + (size_t)r0 * NL,
                 Cc + (size_t)dst * CMS + (size_t)r0 * NL, lds);
    }
}

// ---------------- k_main: out = Cc_j @ H^T (identical to R17) ---------------
__global__ __launch_bounds__(256) void k_main(const unsigned short* __restrict__ Cc,
                                              const unsigned short* __restrict__ H,
                                              float* __restrict__ out) {
    int bid = blockIdx.x;
    int e = ((bid & 7) << 6) | (bid >> 3);  // XCD gets contiguous span
    int ct = e >> 2, bt = (e >> 1) & 1, jh = e & 1;
    __shared__ __align__(16) char lds[49152];
    char* lB = lds;  // 32 KB swizzled H tile
    int t = threadIdx.x;
    const unsigned short* Bg = H + (size_t)(ct * 128) * NL;
    for (int i = t; i < 2048; i += 256) {
        int row = i >> 4, c = i & 15;
        int sw = (c * 16) ^ ((row & 7) << 4);
        *(bf16x8_t*)(lB + row * 256 + sw) =
            *(const bf16x8_t*)(Bg + (size_t)row * NL + c * 8);
    }
    __syncthreads();
    int w = t >> 6, lane = t & 63;
    int wr = (w >> 1) * 64;   // wave b-row offset
    int wc = (w & 1) * 64;    // wave col offset
    int r = lane & 15, g = lane >> 4;
    char* slab = lds + 32768 + w * 4096;  // wave-private 4 KB bounce

    for (int mf = 0; mf < 4; ++mf) {
        int brow_base = bt * 128 + wr + mf * 16;
#pragma unroll
        for (int g0 = 0; g0 < 2; ++g0) {
            bf16x8_t av[4][4];
#pragma unroll
            for (int jj4 = 0; jj4 < 4; ++jj4) {
                int j = jh * 8 + g0 * 4 + jj4;
                const unsigned short* Arow =
                    Cc + (size_t)j * CMS + (size_t)(brow_base + r) * NL;
#pragma unroll
                for (int kk = 0; kk < 4; ++kk)
                    av[jj4][kk] = *(const bf16x8_t*)(Arow + (kk * 4 + g) * 8);
            }
            for (int nf = 0; nf < 4; ++nf) {
                int nn = (w & 1) * 4 + nf;
                int rowB = wc + nf * 16 + r;
                bf16x8_t bvv[4];
#pragma unroll
                for (int kk = 0; kk < 4; ++kk)
                    bvv[kk] = *(const bf16x8_t*)(
                        lB + rowB * 256 + (((kk * 4 + g) * 16) ^ ((rowB & 7) << 4)));
                f32x4_t acc4[4];
#pragma unroll
                for (int q = 0; q < 4; ++q) acc4[q] = (f32x4_t){0.f, 0.f, 0.f, 0.f};
#pragma unroll
                for (int jj4 = 0; jj4 < 4; ++jj4)
#pragma unroll
                    for (int kk = 0; kk < 4; ++kk)
                        acc4[jj4] = __builtin_amdgcn_mfma_f32_16x16x32_bf16(
                            bvv[kk], av[jj4][kk], acc4[jj4], 0, 0, 0);
#pragma unroll
                for (int jj4 = 0; jj4 < 4; ++jj4) {
                    int boff = r * 256 + ((jj4 * 64 + g * 16 + r * 32) & 255);
                    *(f32x4_t*)(slab + boff) = acc4[jj4];
                }
#pragma unroll
                for (int i2 = 0; i2 < 4; ++i2) {
                    int lin = i2 * 1024 + lane * 16;
                    int rs = lin >> 8, cb = lin & 255;
                    f32x4_t v = *(const f32x4_t*)(slab + rs * 256 + ((cb + rs * 32) & 255));
                    size_t o = (size_t)(brow_base + rs) * (NIN * 256) +
                               (size_t)(ct * 8 + nn) * 256 + jh * 128 + g0 * 64 + (cb >> 2);
                    *(f32x4_t*)&out[o] = v;
                }
            }
        }
    }
}

extern "C" void kernel_launch(void* const* d_in, const int* in_sizes, int n_in,
                              void* d_out, int out_size, void* d_ws, size_t ws_size,
                              hipStream_t stream) {
    const float* x = (const float*)d_in[0];
    const float* tf = (const float*)d_in[1];
    const float* tr = (const float*)d_in[2];
    float* out = (float*)d_out;

    // workspace (~9 MB)
    float* W = (float*)d_ws;                              // 20 f32 slots
    float* Cf = W + (size_t)20 * MS;                      // 16 x [256][128] f32
    unsigned short* Wb = (unsigned short*)(Cf + (size_t)16 * CMS);  // 16 bf16 slots
    unsigned short* Fb = Wb + (size_t)16 * MS;            // [1024][128] bf16
    unsigned short* Cc = Fb + (size_t)NIN * NL;           // 16 x [256][128] bf16
    unsigned short* H = Cc + (size_t)16 * CMS;            // [16384][128] bf16 (4 MB)

    static const int grids[5] = {100, 16, 40, 160, 96};
    for (int ph = 0; ph < 5; ++ph) {
        k_phase<<<grids[ph], 256, 0, stream>>>(ph, x, tf, tr, W, Wb, Fb,
                                               Cf, Cc, H);
    }
    k_main<<<512, 256, 0, stream>>>(Cc, H, out);
}

// Round 19
// 141.020 us; speedup vs baseline: 1.6943x; 1.6943x over previous
//
#include <hip/hip_runtime.h>
#include <hip/hip_bf16.h>

#define NIN 1024
#define NL 128
#define MS 16384    // 128x128 matrix slot (elements)
#define CMS 32768   // 256x128 C slot (elements)

typedef __attribute__((ext_vector_type(8))) short bf16x8_t;
typedef __attribute__((ext_vector_type(4))) float f32x4_t;

__device__ inline unsigned short f2bf(float f) {
    __hip_bfloat16 h = __float2bfloat16(f);
    return *reinterpret_cast<unsigned short*>(&h);
}
__device__ inline float bf2f(unsigned short u) {
    unsigned int x = (unsigned int)u << 16;
    return __uint_as_float(x);
}
__device__ inline ushort4 pack4(f32x4_t v) {
    ushort4 o;
    o.x = f2bf(v[0]); o.y = f2bf(v[1]); o.z = f2bf(v[2]); o.w = f2bf(v[3]);
    return o;
}

// ===== chain engine: X(32x128) <- X @ B^n, B fixed, split-bf16 MFMA ========
// LDS map (96 KB): BtHi 32K | BtLo 32K | X0 16K | X1 16K
// Bt layout: row c (=output col), col l (=K), byte(c,l) = c*256 + (2l ^ ((c&7)<<4))
// X layout:  row rr, col c, byte(rr,c) = rr*512 + (4c ^ ((rr&7)<<4))

__device__ __forceinline__ void stageBT(const float* __restrict__ Bg,
                                        unsigned short* BtHi,
                                        unsigned short* BtLo) {
    int t = threadIdx.x;
    for (int idx = t; idx < 4096; idx += 256) {
        int l = idx >> 5, c4 = (idx & 31) * 4;  // read B[l][c4..c4+4)
        f32x4_t v = *(const f32x4_t*)&Bg[(size_t)l * 128 + c4];
#pragma unroll
        for (int q = 0; q < 4; ++q) {
            int c = c4 + q;
            float f = v[q];
            unsigned short hi = f2bf(f);
            unsigned short lo = f2bf(f - bf2f(hi));
            int byt = c * 256 + ((2 * l) ^ ((c & 7) << 4));
            *(unsigned short*)((char*)BtHi + byt) = hi;
            *(unsigned short*)((char*)BtLo + byt) = lo;
        }
    }
}

__device__ __forceinline__ void loadX(const float* __restrict__ Ag, float* X) {
    int t = threadIdx.x;
    for (int idx = t; idx < 1024; idx += 256) {
        int rr = idx >> 5, c4 = (idx & 31) * 4;
        f32x4_t v = *(const f32x4_t*)&Ag[(size_t)rr * 128 + c4];
        *(f32x4_t*)((char*)X + rr * 512 + ((c4 * 4) ^ ((rr & 7) << 4))) = v;
    }
}

__device__ __forceinline__ void chainStage(const float* X, float* Xn,
                                           const unsigned short* BtHi,
                                           const unsigned short* BtLo) {
    int t = threadIdx.x, w = t >> 6, lane = t & 63;
    int r = lane & 15, g = lane >> 4;
    int rt = w & 1, ctb = (w >> 1) * 4;
    int rr = rt * 16 + r;
    int sw = (rr & 7) << 4;
    // load + split A fragments (8 k-contig per kk)
    bf16x8_t avHi[4], avLo[4];
#pragma unroll
    for (int kk = 0; kk < 4; ++kk) {
        int c0 = (kk * 4 + g) * 8;
        f32x4_t x0 = *(const f32x4_t*)((const char*)X + rr * 512 + ((c0 * 4) ^ sw));
        f32x4_t x1 = *(const f32x4_t*)((const char*)X + rr * 512 + (((c0 + 4) * 4) ^ sw));
        bf16x8_t hi, lo;
#pragma unroll
        for (int q = 0; q < 4; ++q) {
            unsigned short h0 = f2bf(x0[q]);
            hi[q] = (short)h0;
            lo[q] = (short)f2bf(x0[q] - bf2f(h0));
            unsigned short h1 = f2bf(x1[q]);
            hi[4 + q] = (short)h1;
            lo[4 + q] = (short)f2bf(x1[q] - bf2f(h1));
        }
        avHi[kk] = hi; avLo[kk] = lo;
    }
#pragma unroll
    for (int ct = 0; ct < 4; ++ct) {
        int cb = (ctb + ct) * 16 + r;  // Bt row (= output col), lane r
        int swb = (cb & 7) << 4;
        f32x4_t acc = (f32x4_t){0.f, 0.f, 0.f, 0.f};
#pragma unroll
        for (int kk = 0; kk < 4; ++kk) {
            int lb2 = (kk * 4 + g) * 16;  // 2*l byte offset
            int byt = cb * 256 + (lb2 ^ swb);
            bf16x8_t bh = *(const bf16x8_t*)((const char*)BtHi + byt);
            bf16x8_t bl = *(const bf16x8_t*)((const char*)BtLo + byt);
            acc = __builtin_amdgcn_mfma_f32_16x16x32_bf16(bh, avHi[kk], acc, 0, 0, 0);
            acc = __builtin_amdgcn_mfma_f32_16x16x32_bf16(bh, avLo[kk], acc, 0, 0, 0);
            acc = __builtin_amdgcn_mfma_f32_16x16x32_bf16(bl, avHi[kk], acc, 0, 0, 0);
        }
        int cc = (ctb + ct) * 16 + g * 4;
        *(f32x4_t*)((char*)Xn + rr * 512 + ((cc * 4) ^ sw)) = acc;
    }
}

__device__ __forceinline__ void writeX(const float* X, float* __restrict__ Df,
                                       unsigned short* __restrict__ Db) {
    int t = threadIdx.x;
    for (int idx = t; idx < 1024; idx += 256) {
        int rr = idx >> 5, c4 = (idx & 31) * 4;
        f32x4_t v = *(const f32x4_t*)((const char*)X + rr * 512 + ((c4 * 4) ^ ((rr & 7) << 4)));
        if (Df) *(f32x4_t*)&Df[(size_t)rr * 128 + c4] = v;
        if (Db) *(ushort4*)&Db[(size_t)rr * 128 + c4] = pack4(v);
    }
}

__device__ __forceinline__ void chainRun(const float* __restrict__ Ag,
                                         const float* __restrict__ Bg, int nst,
                                         float* __restrict__ Df,
                                         unsigned short* __restrict__ Db,
                                         char* lds) {
    unsigned short* BtHi = (unsigned short*)lds;
    unsigned short* BtLo = (unsigned short*)(lds + 32768);
    float* X0 = (float*)(lds + 65536);
    float* X1 = (float*)(lds + 65536 + 16384);
    stageBT(Bg, BtHi, BtLo);
    loadX(Ag, X0);
    __syncthreads();
    float* cur = X0; float* nxt = X1;
    for (int s = 0; s < nst; ++s) {
        chainStage(cur, nxt, BtHi, BtLo);
        __syncthreads();
        float* tmp = cur; cur = nxt; nxt = tmp;
    }
    writeX(cur, Df, Db);
}

// ===== H tile (bf16 MFMA, swapped): H[(n*16+a)][m] = sum_l F[n,l]*T^{a+1}[m,l]
__device__ __forceinline__ void hmfma(const unsigned short* __restrict__ Fb,
                                      const unsigned short* __restrict__ Wa,
                                      unsigned short* __restrict__ H,
                                      int a, int nt, char* lds) {
    char* lB = lds;  // swizzled T tile, 32 KB
    int t = threadIdx.x;
    for (int i = t; i < 2048; i += 256) {
        int row = i >> 4, c = i & 15;
        int sw = (c * 16) ^ ((row & 7) << 4);
        *(bf16x8_t*)(lB + row * 256 + sw) = *(const bf16x8_t*)(Wa + (size_t)row * NL + c * 8);
    }
    __syncthreads();
    int w = t >> 6, lane = t & 63;
    int wn = (w >> 1) * 64, wm = (w & 1) * 64;
    int r = lane & 15, g = lane >> 4;
    const unsigned short* Ag = Fb + (size_t)(nt * 128) * NL;
    bf16x8_t av[4][4];  // [kk][aa]
#pragma unroll
    for (int kk = 0; kk < 4; ++kk) {
        int c16 = kk * 4 + g;
#pragma unroll
        for (int aa = 0; aa < 4; ++aa)
            av[kk][aa] = *(const bf16x8_t*)(Ag + (size_t)(wn + aa * 16 + r) * NL + c16 * 8);
    }
    f32x4_t acc[4][4];
#pragma unroll
    for (int aa = 0; aa < 4; ++aa)
#pragma unroll
        for (int bb = 0; bb < 4; ++bb) acc[aa][bb] = (f32x4_t){0.f, 0.f, 0.f, 0.f};
#pragma unroll
    for (int kk = 0; kk < 4; ++kk) {
        int c16 = kk * 4 + g;
        bf16x8_t bv[4];
#pragma unroll
        for (int bb = 0; bb < 4; ++bb) {
            int rowB = wm + bb * 16 + r;
            bv[bb] = *(const bf16x8_t*)(lB + rowB * 256 + ((c16 * 16) ^ ((rowB & 7) << 4)));
        }
#pragma unroll
        for (int aa = 0; aa < 4; ++aa)
#pragma unroll
            for (int bb = 0; bb < 4; ++bb)
                acc[aa][bb] = __builtin_amdgcn_mfma_f32_16x16x32_bf16(bv[bb], av[kk][aa], acc[aa][bb], 0, 0, 0);
    }
#pragma unroll
    for (int aa = 0; aa < 4; ++aa) {
        int n = nt * 128 + wn + aa * 16 + r;
#pragma unroll
        for (int bb = 0; bb < 4; ++bb) {
            int m0 = wm + bb * 16 + g * 4;
            *(ushort4*)&H[((size_t)n * 16 + a) * NL + m0] = pack4(acc[aa][bb]);
        }
    }
}

// ===== preamble: 3 phases ===================================================
// ph0 (100): lat0(32) | Wb0/Fb copies(64) | T2 = tr@tr chains(4)
// ph1 (56):  T^{3..16}: chains from {T1=tr, T2=W1}, B = T2 (<=7 stages)
// ph2 (248): H(128) | C_j = C0 @ T16^j chains, j=1..15 (120)
__global__ __launch_bounds__(256) void k_phase(int ph,
                                               const float* __restrict__ x,
                                               const float* __restrict__ tf,
                                               const float* __restrict__ tr,
                                               float* __restrict__ W,
                                               unsigned short* __restrict__ Wb,
                                               unsigned short* __restrict__ Fb,
                                               float* __restrict__ Cf,
                                               unsigned short* __restrict__ Cc,
                                               unsigned short* __restrict__ H) {
    __shared__ __align__(16) char lds[98304];
    int blk = blockIdx.x, t = threadIdx.x;
    if (ph == 0) {
        if (blk < 32) {
            // lat0: 8 b-rows per block; thread owns 4 cols (f32x4 tf loads)
            float* xr = (float*)lds;  // [8][1024] 32 KB
            int b0 = blk * 8;
            for (int idx = t; idx < 2048; idx += 256) {
                int rr = idx >> 8, c = idx & 255;
                ((float4*)xr)[rr * 256 + c] =
                    ((const float4*)(x + (size_t)(b0 + rr) * NIN))[c];
            }
            __syncthreads();
            int cg = t & 31, rs = t >> 5;
            const float* xp = xr + rs * NIN;
            f32x4_t acc = (f32x4_t){0.f, 0.f, 0.f, 0.f};
#pragma unroll 8
            for (int i = 0; i < NIN; ++i) {
                f32x4_t tv = *(const f32x4_t*)&tf[i * NL + cg * 4];
                acc += xp[i] * tv;
            }
            int row = b0 + rs;
            *(f32x4_t*)&Cf[(size_t)row * NL + cg * 4] = acc;
            *(ushort4*)&Cc[(size_t)row * NL + cg * 4] = pack4(acc);
        } else if (blk < 96) {
            int id = (blk - 32) * 256 + t;  // 0..16383
            Wb[id] = f2bf(tr[id]);
            for (int i = id; i < NIN * NL; i += 16384) Fb[i] = f2bf(tf[i]);
        } else {
            // T2 = tr @ tr -> W slot 1 (f32 + bf16)
            int r0 = (blk - 96) * 32;
            chainRun(tr + (size_t)r0 * NL, tr, 1,
                     W + MS + (size_t)r0 * NL, Wb + MS + (size_t)r0 * NL, lds);
        }
    } else if (ph == 1) {
        int mi = blk >> 2, r0 = (blk & 3) * 32;  // mi 0..13 -> T^{mi+3}
        int k = mi + 3;
        const float* A = (k & 1) ? tr : (W + MS);      // odd: T1, even: T2
        int nst = (k & 1) ? ((k - 1) / 2) : (k / 2 - 1);
        float* Df = (k == 16) ? (W + 15 * (size_t)MS + (size_t)r0 * NL) : nullptr;
        chainRun(A + (size_t)r0 * NL, W + MS, nst, Df,
                 Wb + (size_t)(k - 1) * MS + (size_t)r0 * NL, lds);
    } else {
        if (blk < 128) {
            hmfma(Fb, Wb + (size_t)(blk >> 3) * MS, H, blk >> 3, blk & 7, lds);
        } else {
            int rel = blk - 128;           // 0..119
            int j = (rel >> 3) + 1;        // 1..15
            int r0 = (rel & 7) * 32;       // C0 row tile
            chainRun(Cf + (size_t)r0 * NL, W + 15 * (size_t)MS, j, nullptr,
                     Cc + (size_t)j * CMS + (size_t)r0 * NL, lds);
        }
    }
}

// ===== k_main: out = Cc_j @ H^T (R17 verbatim) =============================
__global__ __launch_bounds__(256) void k_main(const unsigned short* __restrict__ Cc,
                                              const unsigned short* __restrict__ H,
                                              float* __restrict__ out) {
    int bid = blockIdx.x;
    int e = ((bid & 7) << 6) | (bid >> 3);  // XCD gets contiguous span
    int ct = e >> 2, bt = (e >> 1) & 1, jh = e & 1;
    __shared__ __align__(16) char lds[49152];
    char* lB = lds;  // 32 KB swizzled H tile
    int t = threadIdx.x;
    const unsigned short* Bg = H + (size_t)(ct * 128) * NL;
    for (int i = t; i < 2048; i += 256) {
        int row = i >> 4, c = i & 15;
        int sw = (c * 16) ^ ((row & 7) << 4);
        *(bf16x8_t*)(lB + row * 256 + sw) =
            *(const bf16x8_t*)(Bg + (size_t)row * NL + c * 8);
    }
    __syncthreads();
    int w = t >> 6, lane = t & 63;
    int wr = (w >> 1) * 64;   // wave b-row offset
    int wc = (w & 1) * 64;    // wave col offset
    int r = lane & 15, g = lane >> 4;
    char* slab = lds + 32768 + w * 4096;  // wave-private 4 KB bounce

    for (int mf = 0; mf < 4; ++mf) {
        int brow_base = bt * 128 + wr + mf * 16;
#pragma unroll
        for (int g0 = 0; g0 < 2; ++g0) {
            bf16x8_t av[4][4];
#pragma unroll
            for (int jj4 = 0; jj4 < 4; ++jj4) {
                int j = jh * 8 + g0 * 4 + jj4;
                const unsigned short* Arow =
                    Cc + (size_t)j * CMS + (size_t)(brow_base + r) * NL;
#pragma unroll
                for (int kk = 0; kk < 4; ++kk)
                    av[jj4][kk] = *(const bf16x8_t*)(Arow + (kk * 4 + g) * 8);
            }
            for (int nf = 0; nf < 4; ++nf) {
                int nn = (w & 1) * 4 + nf;
                int rowB = wc + nf * 16 + r;
                bf16x8_t bvv[4];
#pragma unroll
                for (int kk = 0; kk < 4; ++kk)
                    bvv[kk] = *(const bf16x8_t*)(
                        lB + rowB * 256 + (((kk * 4 + g) * 16) ^ ((rowB & 7) << 4)));
                f32x4_t acc4[4];
#pragma unroll
                for (int q = 0; q < 4; ++q) acc4[q] = (f32x4_t){0.f, 0.f, 0.f, 0.f};
#pragma unroll
                for (int jj4 = 0; jj4 < 4; ++jj4)
#pragma unroll
                    for (int kk = 0; kk < 4; ++kk)
                        acc4[jj4] = __builtin_amdgcn_mfma_f32_16x16x32_bf16(
                            bvv[kk], av[jj4][kk], acc4[jj4], 0, 0, 0);
#pragma unroll
                for (int jj4 = 0; jj4 < 4; ++jj4) {
                    int boff = r * 256 + ((jj4 * 64 + g * 16 + r * 32) & 255);
                    *(f32x4_t*)(slab + boff) = acc4[jj4];
                }
#pragma unroll
                for (int i2 = 0; i2 < 4; ++i2) {
                    int lin = i2 * 1024 + lane * 16;
                    int rs = lin >> 8, cb = lin & 255;
                    f32x4_t v = *(const f32x4_t*)(slab + rs * 256 + ((cb + rs * 32) & 255));
                    size_t o = (size_t)(brow_base + rs) * (NIN * 256) +
                               (size_t)(ct * 8 + nn) * 256 + jh * 128 + g0 * 64 + (cb >> 2);
                    *(f32x4_t*)&out[o] = v;
                }
            }
        }
    }
}

extern "C" void kernel_launch(void* const* d_in, const int* in_sizes, int n_in,
                              void* d_out, int out_size, void* d_ws, size_t ws_size,
                              hipStream_t stream) {
    const float* x = (const float*)d_in[0];
    const float* tf = (const float*)d_in[1];
    const float* tr = (const float*)d_in[2];
    float* out = (float*)d_out;

    // workspace (~9 MB)
    float* W = (float*)d_ws;                              // 20 f32 slots
    float* Cf = W + (size_t)20 * MS;                      // C0 f32 [256][128]
    unsigned short* Wb = (unsigned short*)(Cf + (size_t)16 * CMS);  // 16 bf16 slots
    unsigned short* Fb = Wb + (size_t)16 * MS;            // [1024][128] bf16
    unsigned short* Cc = Fb + (size_t)NIN * NL;           // 16 x [256][128] bf16
    unsigned short* H = Cc + (size_t)16 * CMS;            // [16384][128] bf16 (4 MB)

    static const int grids[3] = {100, 56, 248};
    for (int ph = 0; ph < 3; ++ph) {
        k_phase<<<grids[ph], 256, 0, stream>>>(ph, x, tf, tr, W, Wb, Fb,
                                               Cf, Cc, H);
    }
    k_main<<<512, 256, 0, stream>>>(Cc, H, out);
}

// Round 20
// 131.654 us; speedup vs baseline: 1.8148x; 1.0711x over previous
//
#include <hip/hip_runtime.h>
#include <hip/hip_bf16.h>

#define NIN 1024
#define NL 128
#define MS 16384    // 128x128 matrix slot (elements)
#define CMS 32768   // 256x128 C slot (elements)

typedef __attribute__((ext_vector_type(8))) short bf16x8_t;
typedef __attribute__((ext_vector_type(4))) float f32x4_t;

__device__ inline unsigned short f2bf(float f) {
    __hip_bfloat16 h = __float2bfloat16(f);
    return *reinterpret_cast<unsigned short*>(&h);
}
__device__ inline float bf2f(unsigned short u) {
    unsigned int x = (unsigned int)u << 16;
    return __uint_as_float(x);
}
__device__ inline ushort4 pack4(f32x4_t v) {
    ushort4 o;
    o.x = f2bf(v[0]); o.y = f2bf(v[1]); o.z = f2bf(v[2]); o.w = f2bf(v[3]);
    return o;
}

// ===== chain engine: X(32x128) <- X @ B^n, B fixed, split-bf16 MFMA ========
// LDS map (96 KB): BtHi 32K | BtLo 32K | X0 16K | X1 16K
__device__ __forceinline__ void stageBT(const float* __restrict__ Bg,
                                        unsigned short* BtHi,
                                        unsigned short* BtLo) {
    int t = threadIdx.x;
    for (int idx = t; idx < 4096; idx += 256) {
        int l = idx >> 5, c4 = (idx & 31) * 4;  // read B[l][c4..c4+4)
        f32x4_t v = *(const f32x4_t*)&Bg[(size_t)l * 128 + c4];
#pragma unroll
        for (int q = 0; q < 4; ++q) {
            int c = c4 + q;
            float f = v[q];
            unsigned short hi = f2bf(f);
            unsigned short lo = f2bf(f - bf2f(hi));
            int byt = c * 256 + ((2 * l) ^ ((c & 7) << 4));
            *(unsigned short*)((char*)BtHi + byt) = hi;
            *(unsigned short*)((char*)BtLo + byt) = lo;
        }
    }
}

__device__ __forceinline__ void loadX(const float* __restrict__ Ag, float* X) {
    int t = threadIdx.x;
    for (int idx = t; idx < 1024; idx += 256) {
        int rr = idx >> 5, c4 = (idx & 31) * 4;
        f32x4_t v = *(const f32x4_t*)&Ag[(size_t)rr * 128 + c4];
        *(f32x4_t*)((char*)X + rr * 512 + ((c4 * 4) ^ ((rr & 7) << 4))) = v;
    }
}

__device__ __forceinline__ void chainStage(const float* X, float* Xn,
                                           const unsigned short* BtHi,
                                           const unsigned short* BtLo) {
    int t = threadIdx.x, w = t >> 6, lane = t & 63;
    int r = lane & 15, g = lane >> 4;
    int rt = w & 1, ctb = (w >> 1) * 4;
    int rr = rt * 16 + r;
    int sw = (rr & 7) << 4;
    bf16x8_t avHi[4], avLo[4];
#pragma unroll
    for (int kk = 0; kk < 4; ++kk) {
        int c0 = (kk * 4 + g) * 8;
        f32x4_t x0 = *(const f32x4_t*)((const char*)X + rr * 512 + ((c0 * 4) ^ sw));
        f32x4_t x1 = *(const f32x4_t*)((const char*)X + rr * 512 + (((c0 + 4) * 4) ^ sw));
        bf16x8_t hi, lo;
#pragma unroll
        for (int q = 0; q < 4; ++q) {
            unsigned short h0 = f2bf(x0[q]);
            hi[q] = (short)h0;
            lo[q] = (short)f2bf(x0[q] - bf2f(h0));
            unsigned short h1 = f2bf(x1[q]);
            hi[4 + q] = (short)h1;
            lo[4 + q] = (short)f2bf(x1[q] - bf2f(h1));
        }
        avHi[kk] = hi; avLo[kk] = lo;
    }
#pragma unroll
    for (int ct = 0; ct < 4; ++ct) {
        int cb = (ctb + ct) * 16 + r;
        int swb = (cb & 7) << 4;
        f32x4_t acc = (f32x4_t){0.f, 0.f, 0.f, 0.f};
#pragma unroll
        for (int kk = 0; kk < 4; ++kk) {
            int lb2 = (kk * 4 + g) * 16;
            int byt = cb * 256 + (lb2 ^ swb);
            bf16x8_t bh = *(const bf16x8_t*)((const char*)BtHi + byt);
            bf16x8_t bl = *(const bf16x8_t*)((const char*)BtLo + byt);
            acc = __builtin_amdgcn_mfma_f32_16x16x32_bf16(bh, avHi[kk], acc, 0, 0, 0);
            acc = __builtin_amdgcn_mfma_f32_16x16x32_bf16(bh, avLo[kk], acc, 0, 0, 0);
            acc = __builtin_amdgcn_mfma_f32_16x16x32_bf16(bl, avHi[kk], acc, 0, 0, 0);
        }
        int cc = (ctb + ct) * 16 + g * 4;
        *(f32x4_t*)((char*)Xn + rr * 512 + ((cc * 4) ^ sw)) = acc;
    }
}

__device__ __forceinline__ void writeX(const float* X, float* __restrict__ Df,
                                       unsigned short* __restrict__ Db) {
    int t = threadIdx.x;
    for (int idx = t; idx < 1024; idx += 256) {
        int rr = idx >> 5, c4 = (idx & 31) * 4;
        f32x4_t v = *(const f32x4_t*)((const char*)X + rr * 512 + ((c4 * 4) ^ ((rr & 7) << 4)));
        if (Df) *(f32x4_t*)&Df[(size_t)rr * 128 + c4] = v;
        if (Db) *(ushort4*)&Db[(size_t)rr * 128 + c4] = pack4(v);
    }
}

__device__ __forceinline__ void chainRun(const float* __restrict__ Ag,
                                         const float* __restrict__ Bg, int nst,
                                         float* __restrict__ Df,
                                         unsigned short* __restrict__ Db,
                                         char* lds) {
    unsigned short* BtHi = (unsigned short*)lds;
    unsigned short* BtLo = (unsigned short*)(lds + 32768);
    float* X0 = (float*)(lds + 65536);
    float* X1 = (float*)(lds + 65536 + 16384);
    stageBT(Bg, BtHi, BtLo);
    loadX(Ag, X0);
    __syncthreads();
    float* cur = X0; float* nxt = X1;
    for (int s = 0; s < nst; ++s) {
        chainStage(cur, nxt, BtHi, BtLo);
        __syncthreads();
        float* tmp = cur; cur = nxt; nxt = tmp;
    }
    writeX(cur, Df, Db);
}

// ===== H tile (bf16 MFMA, swapped): H[(n*16+a)][m] = sum_l F[n,l]*T^{a+1}[m,l]
__device__ __forceinline__ void hmfma(const unsigned short* __restrict__ Fb,
                                      const unsigned short* __restrict__ Wa,
                                      unsigned short* __restrict__ H,
                                      int a, int nt, char* lds) {
    char* lB = lds;  // swizzled T tile, 32 KB
    int t = threadIdx.x;
    for (int i = t; i < 2048; i += 256) {
        int row = i >> 4, c = i & 15;
        int sw = (c * 16) ^ ((row & 7) << 4);
        *(bf16x8_t*)(lB + row * 256 + sw) = *(const bf16x8_t*)(Wa + (size_t)row * NL + c * 8);
    }
    __syncthreads();
    int w = t >> 6, lane = t & 63;
    int wn = (w >> 1) * 64, wm = (w & 1) * 64;
    int r = lane & 15, g = lane >> 4;
    const unsigned short* Ag = Fb + (size_t)(nt * 128) * NL;
    bf16x8_t av[4][4];
#pragma unroll
    for (int kk = 0; kk < 4; ++kk) {
        int c16 = kk * 4 + g;
#pragma unroll
        for (int aa = 0; aa < 4; ++aa)
            av[kk][aa] = *(const bf16x8_t*)(Ag + (size_t)(wn + aa * 16 + r) * NL + c16 * 8);
    }
    f32x4_t acc[4][4];
#pragma unroll
    for (int aa = 0; aa < 4; ++aa)
#pragma unroll
        for (int bb = 0; bb < 4; ++bb) acc[aa][bb] = (f32x4_t){0.f, 0.f, 0.f, 0.f};
#pragma unroll
    for (int kk = 0; kk < 4; ++kk) {
        int c16 = kk * 4 + g;
        bf16x8_t bv[4];
#pragma unroll
        for (int bb = 0; bb < 4; ++bb) {
            int rowB = wm + bb * 16 + r;
            bv[bb] = *(const bf16x8_t*)(lB + rowB * 256 + ((c16 * 16) ^ ((rowB & 7) << 4)));
        }
#pragma unroll
        for (int aa = 0; aa < 4; ++aa)
#pragma unroll
            for (int bb = 0; bb < 4; ++bb)
                acc[aa][bb] = __builtin_amdgcn_mfma_f32_16x16x32_bf16(bv[bb], av[kk][aa], acc[aa][bb], 0, 0, 0);
    }
#pragma unroll
    for (int aa = 0; aa < 4; ++aa) {
        int n = nt * 128 + wn + aa * 16 + r;
#pragma unroll
        for (int bb = 0; bb < 4; ++bb) {
            int m0 = wm + bb * 16 + g * 4;
            *(ushort4*)&H[((size_t)n * 16 + a) * NL + m0] = pack4(acc[aa][bb]);
        }
    }
}

// ===== preamble: 2 phases ===================================================
// ph0 (156): lat0(32) | Wb0/Fb copies(64) | T^{2..16} chains from tr (60)
// ph1 (248): H(128) | C_j = C0 @ T16^j chains, j=1..15 (120)
__global__ __launch_bounds__(256) void k_phase(int ph,
                                               const float* __restrict__ x,
                                               const float* __restrict__ tf,
                                               const float* __restrict__ tr,
                                               float* __restrict__ W,
                                               unsigned short* __restrict__ Wb,
                                               unsigned short* __restrict__ Fb,
                                               float* __restrict__ Cf,
                                               unsigned short* __restrict__ Cc,
                                               unsigned short* __restrict__ H) {
    __shared__ __align__(16) char lds[98304];
    int blk = blockIdx.x, t = threadIdx.x;
    if (ph == 0) {
        if (blk < 32) {
            float* xr = (float*)lds;  // [8][1024] 32 KB
            int b0 = blk * 8;
            for (int idx = t; idx < 2048; idx += 256) {
                int rr = idx >> 8, c = idx & 255;
                ((float4*)xr)[rr * 256 + c] =
                    ((const float4*)(x + (size_t)(b0 + rr) * NIN))[c];
            }
            __syncthreads();
            int cg = t & 31, rs = t >> 5;
            const float* xp = xr + rs * NIN;
            f32x4_t acc = (f32x4_t){0.f, 0.f, 0.f, 0.f};
#pragma unroll 8
            for (int i = 0; i < NIN; ++i) {
                f32x4_t tv = *(const f32x4_t*)&tf[i * NL + cg * 4];
                acc += xp[i] * tv;
            }
            int row = b0 + rs;
            *(f32x4_t*)&Cf[(size_t)row * NL + cg * 4] = acc;
            *(ushort4*)&Cc[(size_t)row * NL + cg * 4] = pack4(acc);
        } else if (blk < 96) {
            int id = (blk - 32) * 256 + t;  // 0..16383
            Wb[id] = f2bf(tr[id]);
            for (int i = id; i < NIN * NL; i += 16384) Fb[i] = f2bf(tf[i]);
        } else {
            // T^k = tr^k: chain A = tr rows, B = tr, k-1 stages (k = 2..16)
            int mi = (blk - 96) >> 2, r0 = (blk & 3) * 32;
            int k = mi + 2;
            float* Df = (k == 16) ? (W + 15 * (size_t)MS + (size_t)r0 * NL) : nullptr;
            chainRun(tr + (size_t)r0 * NL, tr, k - 1, Df,
                     Wb + (size_t)(k - 1) * MS + (size_t)r0 * NL, lds);
        }
    } else {
        if (blk < 128) {
            hmfma(Fb, Wb + (size_t)(blk >> 3) * MS, H, blk >> 3, blk & 7, lds);
        } else {
            int rel = blk - 128;           // 0..119
            int j = (rel >> 3) + 1;        // 1..15
            int r0 = (rel & 7) * 32;       // C0 row tile
            chainRun(Cf + (size_t)r0 * NL, W + 15 * (size_t)MS, j, nullptr,
                     Cc + (size_t)j * CMS + (size_t)r0 * NL, lds);
        }
    }
}

// ===== k_main: out = Cc_j @ H^T — grid 1024, 4 j per block, 3 blk/CU =======
__global__ __launch_bounds__(256) void k_main(const unsigned short* __restrict__ Cc,
                                              const unsigned short* __restrict__ H,
                                              float* __restrict__ out) {
    int bid = blockIdx.x;
    int e = ((bid & 7) << 7) | (bid >> 3);  // XCD gets contiguous span
    int ct = e >> 3, bt = (e >> 2) & 1, jq = e & 3;
    __shared__ __align__(16) char lds[49152];
    char* lB = lds;  // 32 KB swizzled H tile
    int t = threadIdx.x;
    const unsigned short* Bg = H + (size_t)(ct * 128) * NL;
    for (int i = t; i < 2048; i += 256) {
        int row = i >> 4, c = i & 15;
        int sw = (c * 16) ^ ((row & 7) << 4);
        *(bf16x8_t*)(lB + row * 256 + sw) =
            *(const bf16x8_t*)(Bg + (size_t)row * NL + c * 8);
    }
    __syncthreads();
    int w = t >> 6, lane = t & 63;
    int wr = (w >> 1) * 64;   // wave b-row offset
    int wc = (w & 1) * 64;    // wave col offset
    int r = lane & 15, g = lane >> 4;
    char* slab = lds + 32768 + w * 4096;  // wave-private 4 KB bounce

    for (int mf = 0; mf < 4; ++mf) {
        int brow_base = bt * 128 + wr + mf * 16;
        // hoist A fragments: av[jj4][kk] for this block's 4 j values
        bf16x8_t av[4][4];
#pragma unroll
        for (int jj4 = 0; jj4 < 4; ++jj4) {
            int j = jq * 4 + jj4;
            const unsigned short* Arow =
                Cc + (size_t)j * CMS + (size_t)(brow_base + r) * NL;
#pragma unroll
            for (int kk = 0; kk < 4; ++kk)
                av[jj4][kk] = *(const bf16x8_t*)(Arow + (kk * 4 + g) * 8);
        }
        for (int nf = 0; nf < 4; ++nf) {
            int nn = (w & 1) * 4 + nf;
            int rowB = wc + nf * 16 + r;
            bf16x8_t bvv[4];
#pragma unroll
            for (int kk = 0; kk < 4; ++kk)
                bvv[kk] = *(const bf16x8_t*)(
                    lB + rowB * 256 + (((kk * 4 + g) * 16) ^ ((rowB & 7) << 4)));
            f32x4_t acc4[4];
#pragma unroll
            for (int q = 0; q < 4; ++q) acc4[q] = (f32x4_t){0.f, 0.f, 0.f, 0.f};
#pragma unroll
            for (int jj4 = 0; jj4 < 4; ++jj4)
#pragma unroll
                for (int kk = 0; kk < 4; ++kk)
                    acc4[jj4] = __builtin_amdgcn_mfma_f32_16x16x32_bf16(
                        bvv[kk], av[jj4][kk], acc4[jj4], 0, 0, 0);
            // bounce through wave-private slab -> contiguous 256B-run stores
#pragma unroll
            for (int jj4 = 0; jj4 < 4; ++jj4) {
                int boff = r * 256 + ((jj4 * 64 + g * 16 + r * 32) & 255);
                *(f32x4_t*)(slab + boff) = acc4[jj4];
            }
#pragma unroll
            for (int i2 = 0; i2 < 4; ++i2) {
                int lin = i2 * 1024 + lane * 16;
                int rs = lin >> 8, cb = lin & 255;
                f32x4_t v = *(const f32x4_t*)(slab + rs * 256 + ((cb + rs * 32) & 255));
                size_t o = (size_t)(brow_base + rs) * (NIN * 256) +
                           (size_t)(ct * 8 + nn) * 256 + jq * 64 + (cb >> 2);
                *(f32x4_t*)&out[o] = v;
            }
        }
    }
}

extern "C" void kernel_launch(void* const* d_in, const int* in_sizes, int n_in,
                              void* d_out, int out_size, void* d_ws, size_t ws_size,
                              hipStream_t stream) {
    const float* x = (const float*)d_in[0];
    const float* tf = (const float*)d_in[1];
    const float* tr = (const float*)d_in[2];
    float* out = (float*)d_out;

    // workspace (~9 MB)
    float* W = (float*)d_ws;                              // 20 f32 slots
    float* Cf = W + (size_t)20 * MS;                      // C0 f32 [256][128]
    unsigned short* Wb = (unsigned short*)(Cf + (size_t)16 * CMS);  // 16 bf16 slots
    unsigned short* Fb = Wb + (size_t)16 * MS;            // [1024][128] bf16
    unsigned short* Cc = Fb + (size_t)NIN * NL;           // 16 x [256][128] bf16
    unsigned short* H = Cc + (size_t)16 * CMS;            // [16384][128] bf16 (4 MB)

    static const int grids[2] = {156, 248};
    for (int ph = 0; ph < 2; ++ph) {
        k_phase<<<grids[ph], 256, 0, stream>>>(ph, x, tf, tr, W, Wb, Fb,
                                               Cf, Cc, H);
    }
    k_main<<<1024, 256, 0, stream>>>(Cc, H, out);
}

// Round 21
// 105.121 us; speedup vs baseline: 2.2729x; 1.2524x over previous
//
#include <hip/hip_runtime.h>
#include <hip/hip_bf16.h>

#define NIN 1024
#define NL 128
#define CMS 32768   // 256x128 C slot (elements)
#define MAGIC 0x4D474331

typedef __attribute__((ext_vector_type(8))) short bf16x8_t;
typedef __attribute__((ext_vector_type(4))) float f32x4_t;

__device__ inline unsigned short f2bf(float f) {
    __hip_bfloat16 h = __float2bfloat16(f);
    return *reinterpret_cast<unsigned short*>(&h);
}
__device__ inline float bf2f(unsigned short u) {
    unsigned int x = (unsigned int)u << 16;
    return __uint_as_float(x);
}
__device__ inline ushort4 pack4(f32x4_t v) {
    ushort4 o;
    o.x = f2bf(v[0]); o.y = f2bf(v[1]); o.z = f2bf(v[2]); o.w = f2bf(v[3]);
    return o;
}

// ===== chain engine: X(32x128) <- X @ B, B fixed (split-bf16, 3-MFMA) ======
// LDS map (96 KB): BtHi 32K | BtLo 32K | X0 16K | X1 16K
// Bt[c][l]: byte(c,l) = c*256 + (2l ^ ((c&7)<<4));  X: rr*512 + (4c ^ ((rr&7)<<4))

// Bt[c][l] = B[l][c]  (B in normal orientation, f32 global)
__device__ __forceinline__ void stageBT(const float* __restrict__ Bg,
                                        unsigned short* BtHi, unsigned short* BtLo) {
    int t = threadIdx.x;
    for (int idx = t; idx < 4096; idx += 256) {
        int l = idx >> 5, c4 = (idx & 31) * 4;
        f32x4_t v = *(const f32x4_t*)&Bg[(size_t)l * 128 + c4];
#pragma unroll
        for (int q = 0; q < 4; ++q) {
            int c = c4 + q;
            float f = v[q];
            unsigned short hi = f2bf(f);
            unsigned short lo = f2bf(f - bf2f(hi));
            int byt = c * 256 + ((2 * l) ^ ((c & 7) << 4));
            *(unsigned short*)((char*)BtHi + byt) = hi;
            *(unsigned short*)((char*)BtLo + byt) = lo;
        }
    }
}

// Bt[c][l] = Btr[c][l]  (i.e. effective B = Btr^T; contiguous row reads)
__device__ __forceinline__ void stageBT_T(const float* __restrict__ Btr,
                                          unsigned short* BtHi, unsigned short* BtLo) {
    int t = threadIdx.x;
    for (int idx = t; idx < 4096; idx += 256) {
        int c = idx >> 5, l4 = (idx & 31) * 4;
        f32x4_t v = *(const f32x4_t*)&Btr[(size_t)c * 128 + l4];
        ushort4 hi, lo;
        hi.x = f2bf(v[0]); lo.x = f2bf(v[0] - bf2f(hi.x));
        hi.y = f2bf(v[1]); lo.y = f2bf(v[1] - bf2f(hi.y));
        hi.z = f2bf(v[2]); lo.z = f2bf(v[2] - bf2f(hi.z));
        hi.w = f2bf(v[3]); lo.w = f2bf(v[3] - bf2f(hi.w));
        int byt = c * 256 + ((2 * l4) ^ ((c & 7) << 4));
        *(ushort4*)((char*)BtHi + byt) = hi;
        *(ushort4*)((char*)BtLo + byt) = lo;
    }
}

__device__ __forceinline__ void loadX(const float* __restrict__ Ag, float* X) {
    int t = threadIdx.x;
    for (int idx = t; idx < 1024; idx += 256) {
        int rr = idx >> 5, c4 = (idx & 31) * 4;
        f32x4_t v = *(const f32x4_t*)&Ag[(size_t)rr * 128 + c4];
        *(f32x4_t*)((char*)X + rr * 512 + ((c4 * 4) ^ ((rr & 7) << 4))) = v;
    }
}

__device__ __forceinline__ void chainStage(const float* X, float* Xn,
                                           const unsigned short* BtHi,
                                           const unsigned short* BtLo) {
    int t = threadIdx.x, w = t >> 6, lane = t & 63;
    int r = lane & 15, g = lane >> 4;
    int rt = w & 1, ctb = (w >> 1) * 4;
    int rr = rt * 16 + r;
    int sw = (rr & 7) << 4;
    bf16x8_t avHi[4], avLo[4];
#pragma unroll
    for (int kk = 0; kk < 4; ++kk) {
        int c0 = (kk * 4 + g) * 8;
        f32x4_t x0 = *(const f32x4_t*)((const char*)X + rr * 512 + ((c0 * 4) ^ sw));
        f32x4_t x1 = *(const f32x4_t*)((const char*)X + rr * 512 + (((c0 + 4) * 4) ^ sw));
        bf16x8_t hi, lo;
#pragma unroll
        for (int q = 0; q < 4; ++q) {
            unsigned short h0 = f2bf(x0[q]);
            hi[q] = (short)h0;
            lo[q] = (short)f2bf(x0[q] - bf2f(h0));
            unsigned short h1 = f2bf(x1[q]);
            hi[4 + q] = (short)h1;
            lo[4 + q] = (short)f2bf(x1[q] - bf2f(h1));
        }
        avHi[kk] = hi; avLo[kk] = lo;
    }
#pragma unroll
    for (int ct = 0; ct < 4; ++ct) {
        int cb = (ctb + ct) * 16 + r;
        int swb = (cb & 7) << 4;
        f32x4_t acc = (f32x4_t){0.f, 0.f, 0.f, 0.f};
#pragma unroll
        for (int kk = 0; kk < 4; ++kk) {
            int lb2 = (kk * 4 + g) * 16;
            int byt = cb * 256 + (lb2 ^ swb);
            bf16x8_t bh = *(const bf16x8_t*)((const char*)BtHi + byt);
            bf16x8_t bl = *(const bf16x8_t*)((const char*)BtLo + byt);
            acc = __builtin_amdgcn_mfma_f32_16x16x32_bf16(bh, avHi[kk], acc, 0, 0, 0);
            acc = __builtin_amdgcn_mfma_f32_16x16x32_bf16(bh, avLo[kk], acc, 0, 0, 0);
            acc = __builtin_amdgcn_mfma_f32_16x16x32_bf16(bl, avHi[kk], acc, 0, 0, 0);
        }
        int cc = (ctb + ct) * 16 + g * 4;
        *(f32x4_t*)((char*)Xn + rr * 512 + ((cc * 4) ^ sw)) = acc;
    }
}

__device__ __forceinline__ void writeXf(const float* X, float* __restrict__ Df) {
    int t = threadIdx.x;
    for (int idx = t; idx < 1024; idx += 256) {
        int rr = idx >> 5, c4 = (idx & 31) * 4;
        f32x4_t v = *(const f32x4_t*)((const char*)X + rr * 512 + ((c4 * 4) ^ ((rr & 7) << 4)));
        *(f32x4_t*)&Df[(size_t)rr * 128 + c4] = v;
    }
}

__device__ __forceinline__ void writeXbf(const float* X,
                                         unsigned short* __restrict__ base, int rstride) {
    int t = threadIdx.x;
    for (int idx = t; idx < 1024; idx += 256) {
        int rr = idx >> 5, c4 = (idx & 31) * 4;
        f32x4_t v = *(const f32x4_t*)((const char*)X + rr * 512 + ((c4 * 4) ^ ((rr & 7) << 4)));
        *(ushort4*)&base[(size_t)rr * rstride + c4] = pack4(v);
    }
}

// ===== k_pre: one kernel, warm-idempotent done-cells ========================
// blk 0..31:  lat0 rows blk*8..+8 -> Cf, Cc0; cell[blk]=MAGIC
// blk 32..35: T16 = tr^16 chain (15 stages) rows (blk-32)*32; cell[blk]=MAGIC
// blk 36..67: H-scan: X0 = F rows, B = tr^T, 16 stages, write H_a each stage
// blk 68..75: C-scan: wait cells; X0 = C0 rows, B = T16, 15 stages -> Cc_j
__global__ __launch_bounds__(256) void k_pre(const float* __restrict__ x,
                                             const float* __restrict__ tf,
                                             const float* __restrict__ tr,
                                             float* __restrict__ T16f,
                                             float* __restrict__ Cf,
                                             unsigned short* __restrict__ Cc,
                                             unsigned short* __restrict__ H,
                                             int* __restrict__ cells) {
    __shared__ __align__(16) char lds[98304];
    unsigned short* BtHi = (unsigned short*)lds;
    unsigned short* BtLo = (unsigned short*)(lds + 32768);
    float* X0 = (float*)(lds + 65536);
    float* X1 = (float*)(lds + 65536 + 16384);
    int blk = blockIdx.x, t = threadIdx.x;

    if (blk < 32) {
        // lat0: 8 b-rows; thread owns 4 cols (f32x4 tf loads)
        float* xr = (float*)lds;  // [8][1024] 32 KB
        int b0 = blk * 8;
        for (int idx = t; idx < 2048; idx += 256) {
            int rr = idx >> 8, c = idx & 255;
            ((float4*)xr)[rr * 256 + c] =
                ((const float4*)(x + (size_t)(b0 + rr) * NIN))[c];
        }
        __syncthreads();
        int cg = t & 31, rs = t >> 5;
        const float* xp = xr + rs * NIN;
        f32x4_t acc = (f32x4_t){0.f, 0.f, 0.f, 0.f};
#pragma unroll 8
        for (int i = 0; i < NIN; ++i) {
            f32x4_t tv = *(const f32x4_t*)&tf[i * NL + cg * 4];
            acc += xp[i] * tv;
        }
        int row = b0 + rs;
        *(f32x4_t*)&Cf[(size_t)row * NL + cg * 4] = acc;
        *(ushort4*)&Cc[(size_t)row * NL + cg * 4] = pack4(acc);
        __syncthreads();  // drains stores (vmcnt0 before barrier)
        if (t == 0)
            __hip_atomic_store(&cells[blk], MAGIC, __ATOMIC_RELEASE,
                               __HIP_MEMORY_SCOPE_AGENT);
    } else if (blk < 36) {
        // T16 chain: rows r0..r0+32 of tr, B = tr, 15 stages -> T16f (f32)
        int r0 = (blk - 32) * 32;
        stageBT(tr, BtHi, BtLo);
        loadX(tr + (size_t)r0 * NL, X0);
        __syncthreads();
        float* cur = X0; float* nxt = X1;
        for (int s = 0; s < 15; ++s) {
            chainStage(cur, nxt, BtHi, BtLo);
            __syncthreads();
            float* tmp = cur; cur = nxt; nxt = tmp;
        }
        writeXf(cur, T16f + (size_t)r0 * NL);
        __syncthreads();
        if (t == 0)
            __hip_atomic_store(&cells[blk], MAGIC, __ATOMIC_RELEASE,
                               __HIP_MEMORY_SCOPE_AGENT);
    } else if (blk < 68) {
        // H-scan: X0 = F rows n0..n0+32, B = tr^T; stage s gives H_{s-1}
        int n0 = (blk - 36) * 32;
        stageBT_T(tr, BtHi, BtLo);
        loadX(tf + (size_t)n0 * NL, X0);
        __syncthreads();
        float* cur = X0; float* nxt = X1;
        for (int s = 1; s <= 16; ++s) {
            chainStage(cur, nxt, BtHi, BtLo);
            __syncthreads();
            writeXbf(nxt, H + ((size_t)n0 * 16 + (s - 1)) * NL, 16 * NL);
            float* tmp = cur; cur = nxt; nxt = tmp;
        }
    } else {
        // C-scan: wait for lat0 (4 cells) + T16 (4 cells), then 15 stages
        int cb = blk - 68, r0 = cb * 32;
        if (t == 0) {
#pragma unroll
            for (int q = 0; q < 8; ++q) {
                int ci = (q < 4) ? (cb * 4 + q) : (32 + q - 4);
                for (int it = 0; it < (1 << 22); ++it) {
                    if (__hip_atomic_load(&cells[ci], __ATOMIC_ACQUIRE,
                                          __HIP_MEMORY_SCOPE_AGENT) == MAGIC)
                        break;
                    __builtin_amdgcn_s_sleep(2);
                }
            }
            __threadfence();
        }
        __syncthreads();
        stageBT(T16f, BtHi, BtLo);
        loadX(Cf + (size_t)r0 * NL, X0);
        __syncthreads();
        float* cur = X0; float* nxt = X1;
        for (int j = 1; j <= 15; ++j) {
            chainStage(cur, nxt, BtHi, BtLo);
            __syncthreads();
            writeXbf(nxt, Cc + (size_t)j * CMS + (size_t)r0 * NL, NL);
            float* tmp = cur; cur = nxt; nxt = tmp;
        }
    }
}

// ===== k_main: out = Cc_j @ H^T (R20 verbatim) =============================
__global__ __launch_bounds__(256) void k_main(const unsigned short* __restrict__ Cc,
                                              const unsigned short* __restrict__ H,
                                              float* __restrict__ out) {
    int bid = blockIdx.x;
    int e = ((bid & 7) << 7) | (bid >> 3);  // XCD gets contiguous span
    int ct = e >> 3, bt = (e >> 2) & 1, jq = e & 3;
    __shared__ __align__(16) char lds[49152];
    char* lB = lds;  // 32 KB swizzled H tile
    int t = threadIdx.x;
    const unsigned short* Bg = H + (size_t)(ct * 128) * NL;
    for (int i = t; i < 2048; i += 256) {
        int row = i >> 4, c = i & 15;
        int sw = (c * 16) ^ ((row & 7) << 4);
        *(bf16x8_t*)(lB + row * 256 + sw) =
            *(const bf16x8_t*)(Bg + (size_t)row * NL + c * 8);
    }
    __syncthreads();
    int w = t >> 6, lane = t & 63;
    int wr = (w >> 1) * 64;   // wave b-row offset
    int wc = (w & 1) * 64;    // wave col offset
    int r = lane & 15, g = lane >> 4;
    char* slab = lds + 32768 + w * 4096;  // wave-private 4 KB bounce

    for (int mf = 0; mf < 4; ++mf) {
        int brow_base = bt * 128 + wr + mf * 16;
        bf16x8_t av[4][4];
#pragma unroll
        for (int jj4 = 0; jj4 < 4; ++jj4) {
            int j = jq * 4 + jj4;
            const unsigned short* Arow =
                Cc + (size_t)j * CMS + (size_t)(brow_base + r) * NL;
#pragma unroll
            for (int kk = 0; kk < 4; ++kk)
                av[jj4][kk] = *(const bf16x8_t*)(Arow + (kk * 4 + g) * 8);
        }
        for (int nf = 0; nf < 4; ++nf) {
            int nn = (w & 1) * 4 + nf;
            int rowB = wc + nf * 16 + r;
            bf16x8_t bvv[4];
#pragma unroll
            for (int kk = 0; kk < 4; ++kk)
                bvv[kk] = *(const bf16x8_t*)(
                    lB + rowB * 256 + (((kk * 4 + g) * 16) ^ ((rowB & 7) << 4)));
            f32x4_t acc4[4];
#pragma unroll
            for (int q = 0; q < 4; ++q) acc4[q] = (f32x4_t){0.f, 0.f, 0.f, 0.f};
#pragma unroll
            for (int jj4 = 0; jj4 < 4; ++jj4)
#pragma unroll
                for (int kk = 0; kk < 4; ++kk)
                    acc4[jj4] = __builtin_amdgcn_mfma_f32_16x16x32_bf16(
                        bvv[kk], av[jj4][kk], acc4[jj4], 0, 0, 0);
#pragma unroll
            for (int jj4 = 0; jj4 < 4; ++jj4) {
                int boff = r * 256 + ((jj4 * 64 + g * 16 + r * 32) & 255);
                *(f32x4_t*)(slab + boff) = acc4[jj4];
            }
#pragma unroll
            for (int i2 = 0; i2 < 4; ++i2) {
                int lin = i2 * 1024 + lane * 16;
                int rs = lin >> 8, cb = lin & 255;
                f32x4_t v = *(const f32x4_t*)(slab + rs * 256 + ((cb + rs * 32) & 255));
                size_t o = (size_t)(brow_base + rs) * (NIN * 256) +
                           (size_t)(ct * 8 + nn) * 256 + jq * 64 + (cb >> 2);
                *(f32x4_t*)&out[o] = v;
            }
        }
    }
}

extern "C" void kernel_launch(void* const* d_in, const int* in_sizes, int n_in,
                              void* d_out, int out_size, void* d_ws, size_t ws_size,
                              hipStream_t stream) {
    const float* x = (const float*)d_in[0];
    const float* tf = (const float*)d_in[1];
    const float* tr = (const float*)d_in[2];
    float* out = (float*)d_out;

    // workspace (~5.3 MB)
    float* T16f = (float*)d_ws;                           // 16384 f32 (64 KB)
    float* Cf = T16f + 16384;                             // [256][128] f32
    unsigned short* Cc = (unsigned short*)(Cf + (size_t)256 * NL);  // 16 x CMS bf16
    unsigned short* H = Cc + (size_t)16 * CMS;            // [16384][128] bf16 (4 MB)
    int* cells = (int*)(H + (size_t)16384 * NL);          // 64 ints

    k_pre<<<76, 256, 0, stream>>>(x, tf, tr, T16f, Cf, Cc, H, cells);
    k_main<<<1024, 256, 0, stream>>>(Cc, H, out);
}